// Round 8
// baseline (114.083 us; speedup 1.0000x reference)
//
#include <hip/hip_runtime.h>

#define F_IN 128
#define CH   128

typedef __attribute__((ext_vector_type(8))) short bf16x8;
typedef __attribute__((ext_vector_type(4))) float f32x4;
typedef __attribute__((ext_vector_type(2))) float f32x2;
typedef __attribute__((ext_vector_type(2))) unsigned u32x2;

// f32 -> bf16 round-to-nearest-even
static __device__ __forceinline__ ushort f2b(float f) {
  union { float f; unsigned u; } v; v.f = f;
  const unsigned u = v.u;
  return (ushort)((u + 0x7FFFu + ((u >> 16) & 1u)) >> 16);
}

// ---------------------------------------------------------------------------
// Phase 1 (fused): blocks [0, gemm_blocks) do XW = X @ W via bf16 MFMA,
//   then quantize each output row to int8 (offset-binary, per-node scale
//   s[r] = rowmax/127) -> 12.8 MB table + 400 KB scales.
//   256 rows/block via 2 sequential 128-row groups (halves per-block W-staging
//   tax vs R7: 391 blocks instead of 782).
// blocks [gemm_blocks, ...) do row_ptr[r] = lower_bound(edge_row, r).
// mfma_f32_16x16x32_bf16 layouts (guide §3, m89-verified):
//   A frag: row = lane&15, k = (lane>>4)*8 + j
//   B frag: col = lane&15, k = (lane>>4)*8 + j
//   C/D   : col = lane&15, row = (lane>>4)*4 + reg
// ---------------------------------------------------------------------------
__global__ __launch_bounds__(512) void gemm_rowptr_fused(
    const float* __restrict__ x, const float* __restrict__ w,
    unsigned char* __restrict__ xwq, float* __restrict__ scale,
    const int* __restrict__ edge_row, int* __restrict__ row_ptr,
    int n, int n_edges, int gemm_blocks) {
  __shared__ __align__(16) ushort Wt[F_IN * CH];  // W^T, swizzled, 32 KB
  const int t = threadIdx.x;

  if ((int)blockIdx.x >= gemm_blocks) {
    // ---- rowptr tail blocks: CSR offsets from sorted edge_row ----
    const int r = ((int)blockIdx.x - gemm_blocks) * 512 + t;
    if (r <= n) {
      int lo = 0, hi = n_edges;
      while (lo < hi) {
        const int mid = (lo + hi) >> 1;
        if (edge_row[mid] < r) lo = mid + 1; else hi = mid;
      }
      row_ptr[r] = lo;
    }
    return;
  }

  // ---- GEMM blocks ----
  // stage W^T as bf16 with XOR swizzle: byte ^= (col&7)<<4
  for (int i = t; i < (F_IN * CH) / 4; i += 512) {
    const int k  = i >> 5;          // 0..127
    const int n4 = (i & 31) << 2;   // 0,4,...,124
    const f32x4 wv = *(const f32x4*)&w[k * CH + n4];
#pragma unroll
    for (int q = 0; q < 4; ++q) {
      const int nn = n4 + q;
      const int byte = (nn * 256 + k * 2) ^ ((nn & 7) << 4);
      *(ushort*)((char*)Wt + byte) = f2b(wv[q]);
    }
  }
  __syncthreads();

  const int wave = t >> 6, lane = t & 63;
  const int li   = lane & 15;
  const int kgrp = (lane >> 4) * 8;

  for (int grp = 0; grp < 2; ++grp) {
    const int R0   = blockIdx.x * 256 + grp * 128 + wave * 16;
    const int arow = R0 + li;

    // A fragments (4 K-steps), f32->bf16 in-register; x read-once -> nt loads
    bf16x8 a[4];
#pragma unroll
    for (int s = 0; s < 4; ++s) {
      if (arow < n) {
        const f32x4 p0 = __builtin_nontemporal_load(
            (const f32x4*)&x[arow * F_IN + s * 32 + kgrp]);
        const f32x4 p1 = __builtin_nontemporal_load(
            (const f32x4*)&x[arow * F_IN + s * 32 + kgrp + 4]);
#pragma unroll
        for (int j = 0; j < 4; ++j) {
          a[s][j]     = (short)f2b(p0[j]);
          a[s][j + 4] = (short)f2b(p1[j]);
        }
      } else {
#pragma unroll
        for (int j = 0; j < 8; ++j) a[s][j] = (short)0;
      }
    }

    f32x4 acc[8];
#pragma unroll
    for (int t8 = 0; t8 < 8; ++t8) acc[t8] = (f32x4){0.f, 0.f, 0.f, 0.f};

#pragma unroll
    for (int t8 = 0; t8 < 8; ++t8) {
      const int col = t8 * 16 + li;
#pragma unroll
      for (int s = 0; s < 4; ++s) {
        const int byte = (col * 256 + (s * 32 + kgrp) * 2) ^ ((col & 7) << 4);
        const bf16x8 b = *(const bf16x8*)((const char*)Wt + byte);
        acc[t8] = __builtin_amdgcn_mfma_f32_16x16x32_bf16(a[s], b, acc[t8], 0, 0, 0);
      }
    }

    // Epilogue: per-row absmax (shfl over 16 channel-lanes) -> int8 quant.
    const int r0 = R0 + (lane >> 4) * 4;
#pragma unroll
    for (int i = 0; i < 4; ++i) {
      const int rr = r0 + i;
      float m = 0.f;
#pragma unroll
      for (int t8 = 0; t8 < 8; ++t8) m = fmaxf(m, fabsf(acc[t8][i]));
      m = fmaxf(m, __shfl_xor(m, 1));
      m = fmaxf(m, __shfl_xor(m, 2));
      m = fmaxf(m, __shfl_xor(m, 4));
      m = fmaxf(m, __shfl_xor(m, 8));
      const float inv = (m > 1e-20f) ? 127.f / m : 0.f;
      if (rr < n) {
        if (li == 0) scale[rr] = m * (1.f / 127.f);
#pragma unroll
        for (int t8 = 0; t8 < 8; ++t8) {
          // |acc|*inv <= 127 by construction; +128 -> [1,255], no clamp
          const float q = rintf(acc[t8][i] * inv) + 128.f;
          xwq[rr * CH + t8 * 16 + li] = (unsigned char)q;
        }
      }
    }
  }
}

// ---------------------------------------------------------------------------
// Phase 2: SpMM, QUARTER-WAVE per row (R7 structure: 16 lanes own one row,
// lane li owns channels li*8..li*8+7, zero cross-lane acc reduction), now
// SOFTWARE-PIPELINED meta: chunk k+1's col/val/scale loads are issued AFTER
// chunk k's gathers (so the gathers' vmcnt wait doesn't drain them) and stay
// outstanding through chunk k's decode — removing the ~1kcy meta sub-chain
// from the per-chunk critical path (R7 post-mortem: wall = VALU + 46us of
// serial-chain stall).
// Per 16-edge chunk: meta via wave-private LDS slab (2 ds_write + 4
// ds_read_b128 replaces shfl broadcasts); 16 u32x2 gathers batch-issued;
// f32x2 pk_fma decode, unconditional (dummy slots c=0/vp=0).
// -128 offset: scalar S quarter-reduced (4 shfl). Epilogue lane-local.
// ---------------------------------------------------------------------------
#define ACCD(word, j0, vv)                                                \
  do {                                                                    \
    f32x2 lo_, hi_;                                                       \
    lo_[0] = (float)((word) & 0xFFu);                                     \
    lo_[1] = (float)(((word) >> 8) & 0xFFu);                              \
    hi_[0] = (float)(((word) >> 16) & 0xFFu);                             \
    hi_[1] = (float)((word) >> 24);                                       \
    acc2[(j0)]     = __builtin_elementwise_fma(vv, lo_, acc2[(j0)]);      \
    acc2[(j0) + 1] = __builtin_elementwise_fma(vv, hi_, acc2[(j0) + 1]);  \
  } while (0)

#define ACC8PK(U, V)                                                      \
  do {                                                                    \
    const f32x2 vv_ = {(V), (V)};                                         \
    ACCD((U)[0], 0, vv_);                                                 \
    ACCD((U)[1], 2, vv_);                                                 \
  } while (0)

__global__ __launch_bounds__(256) void spmm_qwave(
    const unsigned char* __restrict__ xwq, const float* __restrict__ scale,
    const float* __restrict__ edge_val, const int* __restrict__ edge_col,
    const int* __restrict__ row_ptr, const float* __restrict__ bias,
    float* __restrict__ out, int n) {
  __shared__ int   cbuf[256];
  __shared__ float vbuf[256];
  const int tid = threadIdx.x;
  const int row = (int)((blockIdx.x * 256 + tid) >> 4);
  if (row >= n) return;
  const int li    = tid & 15;    // lane-in-quarter: owns channels li*8..li*8+7
  const int qbase = tid & ~15;   // quarter's LDS base
  const u32x2* __restrict__ xw2 = (const u32x2*)xwq;  // 16 u32x2 per row

  const int start = row_ptr[row], end = row_ptr[row + 1];

  f32x2 acc2[4];
#pragma unroll
  for (int j = 0; j < 4; ++j) acc2[j] = (f32x2){0.f, 0.f};
  float S = 0.f;  // per-lane sum of vp (offset correction)

  // prologue: chunk-0 meta
  int   c_cur = 0;
  float vp_cur = 0.f;
  {
    const int e = start + li;
    if (e < end) {
      c_cur = __builtin_nontemporal_load(edge_col + e);
      vp_cur = __builtin_nontemporal_load(edge_val + e) * scale[c_cur];
    }
  }

  for (int e0 = start; e0 < end; e0 += 16) {
    S += vp_cur;
    cbuf[tid] = c_cur;     // wave-private slab: in-wave DS ordering, no barrier
    vbuf[tid] = vp_cur;

    // batch-issue all 16 gathers (cols read 4-at-a-time via ds_read_b128)
    u32x2 u[16];
#pragma unroll
    for (int it4 = 0; it4 < 4; ++it4) {
      const int4 c4 = *(const int4*)&cbuf[qbase + it4 * 4];
      u[it4 * 4 + 0] = xw2[c4.x * 16 + li];
      u[it4 * 4 + 1] = xw2[c4.y * 16 + li];
      u[it4 * 4 + 2] = xw2[c4.z * 16 + li];
      u[it4 * 4 + 3] = xw2[c4.w * 16 + li];
    }

    // prefetch next chunk's meta AFTER the gathers (issue-order matters:
    // decode's vmcnt wait covers the gathers but leaves these outstanding)
    int   c_nxt = 0;
    float vp_nxt = 0.f;
    {
      const int en = e0 + 16 + li;
      if (en < end) {
        c_nxt = __builtin_nontemporal_load(edge_col + en);
        vp_nxt = __builtin_nontemporal_load(edge_val + en) * scale[c_nxt];
      }
    }

    // decode: unconditional, vp=0 kills dummy slots
#pragma unroll
    for (int it4 = 0; it4 < 4; ++it4) {
      const f32x4 v4 = *(const f32x4*)&vbuf[qbase + it4 * 4];
      ACC8PK(u[it4 * 4 + 0], v4[0]);
      ACC8PK(u[it4 * 4 + 1], v4[1]);
      ACC8PK(u[it4 * 4 + 2], v4[2]);
      ACC8PK(u[it4 * 4 + 3], v4[3]);
    }

    c_cur = c_nxt;
    vp_cur = vp_nxt;
  }

  // S over the quarter's 16 lanes (each owned distinct edges)
  S += __shfl_xor(S, 1);
  S += __shfl_xor(S, 2);
  S += __shfl_xor(S, 4);
  S += __shfl_xor(S, 8);

  // epilogue: lane-local 8 channels, bias+ReLU, direct store — no masking
  const float off = 128.f * S;
  const float* a = (const float*)acc2;
  const int cb = li * 8;
  const f32x4 b0 = *(const f32x4*)&bias[cb];
  const f32x4 b1 = *(const f32x4*)&bias[cb + 4];
  f32x4 o0, o1;
  o0[0] = fmaxf(a[0] - off + b0[0], 0.f);
  o0[1] = fmaxf(a[1] - off + b0[1], 0.f);
  o0[2] = fmaxf(a[2] - off + b0[2], 0.f);
  o0[3] = fmaxf(a[3] - off + b0[3], 0.f);
  o1[0] = fmaxf(a[4] - off + b1[0], 0.f);
  o1[1] = fmaxf(a[5] - off + b1[1], 0.f);
  o1[2] = fmaxf(a[6] - off + b1[2], 0.f);
  o1[3] = fmaxf(a[7] - off + b1[3], 0.f);
  __builtin_nontemporal_store(o0, (f32x4*)&out[(size_t)row * CH + cb]);
  __builtin_nontemporal_store(o1, (f32x4*)&out[(size_t)row * CH + cb + 4]);
}

extern "C" void kernel_launch(void* const* d_in, const int* in_sizes, int n_in,
                              void* d_out, int out_size, void* d_ws, size_t ws_size,
                              hipStream_t stream) {
  const float* x        = (const float*)d_in[0];
  const float* kernel   = (const float*)d_in[1];
  const float* bias     = (const float*)d_in[2];
  const float* edge_val = (const float*)d_in[3];
  const int*   edge_row = (const int*)d_in[4];
  const int*   edge_col = (const int*)d_in[5];
  float* out = (float*)d_out;

  const int n       = in_sizes[0] / F_IN;   // 100000
  const int n_edges = in_sizes[3];          // 3200000

  // ws layout: [xwq: n*CH int8 = 12.8 MB][scale: n f32][row_ptr: (n+1) int]
  unsigned char* xwq = (unsigned char*)d_ws;
  float* scale = (float*)((char*)d_ws + (size_t)n * CH);
  int* rowptr  = (int*)((char*)d_ws + (size_t)n * CH + (size_t)n * sizeof(float));

  // Phase 1 (fused): XW = X @ W (bf16 MFMA) + int8 quant + CSR row_ptr
  const int GB = (n + 255) / 256;           // 256 rows/block (2 groups)
  const int RB = (n + 1 + 511) / 512;
  gemm_rowptr_fused<<<GB + RB, 512, 0, stream>>>(x, kernel, xwq, scale,
                                                 edge_row, rowptr,
                                                 n, n_edges, GB);

  // Phase 2: SpMM + bias + ReLU. 16 rows per 256-thr block (quarter-wave/row).
  const int blocks = (n * 16 + 255) / 256;
  spmm_qwave<<<blocks, 256, 0, stream>>>(xwq, scale, edge_val, edge_col,
                                         rowptr, bias, out, n);
}